// Round 1
// baseline (181.085 us; speedup 1.0000x reference)
//
#include <hip/hip_runtime.h>

// RoiPooling: crop + bilinear 7x7 resize, TF1 resize_bilinear (align_corners=False).
// feat: (128,128,1024) fp32, rois: (512,4) fp32 [ymin,xmin,ymax,xmax], out: (512,7,7,1024) fp32.
//
// One block per (roi, py, px) output cell; 256 threads x float4 = 1024 channels.
// All four corner reads are channel-contiguous -> coalesced dwordx4 loads.

#define POOL_P 7
#define FEAT_C 1024
#define FEAT_W 128

__global__ __launch_bounds__(256) void roi_pool_kernel(
    const float* __restrict__ feat,
    const float* __restrict__ rois,
    float* __restrict__ out)
{
    const int blk = blockIdx.x;              // roi*49 + py*7 + px
    const int px  = blk % POOL_P;
    const int py  = (blk / POOL_P) % POOL_P;
    const int r   = blk / (POOL_P * POOL_P);

    // ROI box (wave-uniform scalar math, replicated across lanes)
    const float4 roi = ((const float4*)rois)[r];
    const int ymin = (int)roi.x;
    const int xmin = (int)roi.y;
    const int ymax = (int)roi.z;
    const int xmax = (int)roi.w;

    const float h = (float)(ymax - ymin + 1);
    const float w = (float)(xmax - xmin + 1);

    const float src_y = (float)py * (h / 7.0f);
    const float src_x = (float)px * (w / 7.0f);

    const int y0 = (int)floorf(src_y);
    const int x0 = (int)floorf(src_x);
    const int y1 = min(y0 + 1, ymax - ymin);
    const int x1 = min(x0 + 1, xmax - xmin);

    const float fy = src_y - (float)y0;
    const float fx = src_x - (float)x0;

    const int gy0 = ymin + y0;
    const int gy1 = ymin + y1;
    const int gx0 = xmin + x0;
    const int gx1 = xmin + x1;

    const float4* __restrict__ tlp = (const float4*)(feat + ((size_t)(gy0 * FEAT_W + gx0)) * FEAT_C);
    const float4* __restrict__ trp = (const float4*)(feat + ((size_t)(gy0 * FEAT_W + gx1)) * FEAT_C);
    const float4* __restrict__ blp = (const float4*)(feat + ((size_t)(gy1 * FEAT_W + gx0)) * FEAT_C);
    const float4* __restrict__ brp = (const float4*)(feat + ((size_t)(gy1 * FEAT_W + gx1)) * FEAT_C);
    float4* __restrict__ op = (float4*)(out + (size_t)blk * FEAT_C);

    const int t = threadIdx.x;               // 0..255 -> one float4 each (1024 ch total)

    const float4 tl = tlp[t];
    const float4 tr = trp[t];
    const float4 bl = blp[t];
    const float4 br = brp[t];

    float4 res;
    {
        float top, bot;
        top = tl.x + (tr.x - tl.x) * fx;
        bot = bl.x + (br.x - bl.x) * fx;
        res.x = top + (bot - top) * fy;
        top = tl.y + (tr.y - tl.y) * fx;
        bot = bl.y + (br.y - bl.y) * fx;
        res.y = top + (bot - top) * fy;
        top = tl.z + (tr.z - tl.z) * fx;
        bot = bl.z + (br.z - bl.z) * fx;
        res.z = top + (bot - top) * fy;
        top = tl.w + (tr.w - tl.w) * fx;
        bot = bl.w + (br.w - bl.w) * fx;
        res.w = top + (bot - top) * fy;
    }
    op[t] = res;
}

extern "C" void kernel_launch(void* const* d_in, const int* in_sizes, int n_in,
                              void* d_out, int out_size, void* d_ws, size_t ws_size,
                              hipStream_t stream) {
    const float* feat = (const float*)d_in[0];   // (1,128,128,1024) fp32
    const float* rois = (const float*)d_in[1];   // (512,4) fp32
    float* out        = (float*)d_out;           // (512, 7*7*1024) fp32

    const int n_rois  = in_sizes[1] / 4;         // 512
    const int n_blocks = n_rois * POOL_P * POOL_P; // 25088

    roi_pool_kernel<<<n_blocks, 256, 0, stream>>>(feat, rois, out);
}

// Round 2
// 170.809 us; speedup vs baseline: 1.0602x; 1.0602x over previous
//
#include <hip/hip_runtime.h>

// RoiPooling: crop + bilinear 7x7 resize, TF1 resize_bilinear (align_corners=False).
// feat: (128,128,1024) fp32, rois: (512,4) fp32 [ymin,xmin,ymax,xmax], out: (512,7,7,1024) fp32.
//
// R2 changes vs R1:
//  - XCD-locality swizzle: hardware round-robins blockIdx%8 across the 8 XCDs.
//    Remap so all 49 cells of one ROI share blockIdx%8 -> one XCD's L2 holds the
//    ROI's ~256KB pixel footprint once instead of 8x (FETCH_SIZE was 2.6x ideal).
//  - 128 threads x 2 float4/thread: 8 independent global loads in flight per
//    thread (was 4) to raise outstanding bytes per wave (BW was only 47% peak).

#define POOL_P 7
#define FEAT_C 1024
#define FEAT_W 128
#define CELLS_PER_ROI (POOL_P * POOL_P)          // 49
#define GROUP_BLOCKS  (8 * CELLS_PER_ROI)        // 392: 8 ROIs x 49 cells

__global__ __launch_bounds__(128) void roi_pool_kernel(
    const float* __restrict__ feat,
    const float* __restrict__ rois,
    float* __restrict__ out)
{
    // ---- XCD swizzle: i%8 is (heuristically) the XCD. Keep it constant per ROI.
    const int i    = blockIdx.x;
    const int q    = i / GROUP_BLOCKS;           // ROI group of 8
    const int k    = i - q * GROUP_BLOCKS;       // [0,392)
    const int r    = 8 * q + (k & 7);            // ROI id: k%8 fixed per ROI
    const int cell = k >> 3;                     // [0,49)
    const int px   = cell % POOL_P;
    const int py   = cell / POOL_P;

    // ---- ROI box (wave-uniform scalar math)
    const float4 roi = ((const float4*)rois)[r];
    const int ymin = (int)roi.x;
    const int xmin = (int)roi.y;
    const int ymax = (int)roi.z;
    const int xmax = (int)roi.w;

    const float h = (float)(ymax - ymin + 1);
    const float w = (float)(xmax - xmin + 1);

    const float src_y = (float)py * (h / 7.0f);
    const float src_x = (float)px * (w / 7.0f);

    const int y0 = (int)floorf(src_y);
    const int x0 = (int)floorf(src_x);
    const int y1 = min(y0 + 1, ymax - ymin);
    const int x1 = min(x0 + 1, xmax - xmin);

    const float fy = src_y - (float)y0;
    const float fx = src_x - (float)x0;

    const int gy0 = ymin + y0;
    const int gy1 = ymin + y1;
    const int gx0 = xmin + x0;
    const int gx1 = xmin + x1;

    const float4* __restrict__ tlp = (const float4*)(feat + ((size_t)(gy0 * FEAT_W + gx0)) * FEAT_C);
    const float4* __restrict__ trp = (const float4*)(feat + ((size_t)(gy0 * FEAT_W + gx1)) * FEAT_C);
    const float4* __restrict__ blp = (const float4*)(feat + ((size_t)(gy1 * FEAT_W + gx0)) * FEAT_C);
    const float4* __restrict__ brp = (const float4*)(feat + ((size_t)(gy1 * FEAT_W + gx1)) * FEAT_C);
    float4* __restrict__ op = (float4*)(out + ((size_t)r * CELLS_PER_ROI + cell) * FEAT_C);

    const int t0 = threadIdx.x;                  // [0,128)
    const int t1 = t0 + 128;

    // Issue all 8 loads before any use (max outstanding vmcnt)
    const float4 tl0 = tlp[t0];
    const float4 tr0 = trp[t0];
    const float4 bl0 = blp[t0];
    const float4 br0 = brp[t0];
    const float4 tl1 = tlp[t1];
    const float4 tr1 = trp[t1];
    const float4 bl1 = blp[t1];
    const float4 br1 = brp[t1];

    float4 res0, res1;
    {
        float top, bot;
        top = tl0.x + (tr0.x - tl0.x) * fx; bot = bl0.x + (br0.x - bl0.x) * fx; res0.x = top + (bot - top) * fy;
        top = tl0.y + (tr0.y - tl0.y) * fx; bot = bl0.y + (br0.y - bl0.y) * fx; res0.y = top + (bot - top) * fy;
        top = tl0.z + (tr0.z - tl0.z) * fx; bot = bl0.z + (br0.z - bl0.z) * fx; res0.z = top + (bot - top) * fy;
        top = tl0.w + (tr0.w - tl0.w) * fx; bot = bl0.w + (br0.w - bl0.w) * fx; res0.w = top + (bot - top) * fy;
        top = tl1.x + (tr1.x - tl1.x) * fx; bot = bl1.x + (br1.x - bl1.x) * fx; res1.x = top + (bot - top) * fy;
        top = tl1.y + (tr1.y - tl1.y) * fx; bot = bl1.y + (br1.y - bl1.y) * fx; res1.y = top + (bot - top) * fy;
        top = tl1.z + (tr1.z - tl1.z) * fx; bot = bl1.z + (br1.z - bl1.z) * fx; res1.z = top + (bot - top) * fy;
        top = tl1.w + (tr1.w - tl1.w) * fx; bot = bl1.w + (br1.w - bl1.w) * fx; res1.w = top + (bot - top) * fy;
    }
    op[t0] = res0;
    op[t1] = res1;
}

extern "C" void kernel_launch(void* const* d_in, const int* in_sizes, int n_in,
                              void* d_out, int out_size, void* d_ws, size_t ws_size,
                              hipStream_t stream) {
    const float* feat = (const float*)d_in[0];   // (1,128,128,1024) fp32
    const float* rois = (const float*)d_in[1];   // (512,4) fp32
    float* out        = (float*)d_out;           // (512, 7*7*1024) fp32

    const int n_rois   = in_sizes[1] / 4;              // 512
    const int n_blocks = n_rois * CELLS_PER_ROI;       // 25088

    roi_pool_kernel<<<n_blocks, 128, 0, stream>>>(feat, rois, out);
}